// Round 1
// baseline (340.418 us; speedup 1.0000x reference)
//
#include <hip/hip_runtime.h>

// RoIAlign (torchvision semantics, aligned=false, sampling_ratio=2)
// features: [N=2, C=256, H=200, W=200] f32
// rois:     [K=1000, 5] f32  (b, x1, y1, x2, y2) raw image coords
// out:      [K, C, 7, 7] f32
constexpr int C = 256, H = 200, W = 200;
constexpr int PH = 7, PW = 7;
constexpr float SCALE = 0.125f;

__global__ __launch_bounds__(256) void roi_align_kernel(
    const float* __restrict__ feat, const float* __restrict__ rois,
    float* __restrict__ out, int total)
{
    int idx = blockIdx.x * blockDim.x + threadIdx.x;
    if (idx >= total) return;

    int pw = idx % PW;
    int ph = (idx / PW) % PH;
    int c  = (idx / (PW * PH)) % C;
    int k  = idx / (PW * PH * C);

    const float* r = rois + (size_t)k * 5;
    int   b  = (int)r[0];
    float x1 = r[1] * SCALE, y1 = r[2] * SCALE;
    float x2 = r[3] * SCALE, y2 = r[4] * SCALE;
    float roi_w = fmaxf(x2 - x1, 1.0f);
    float roi_h = fmaxf(y2 - y1, 1.0f);
    float bin_w = roi_w * (1.0f / PW);
    float bin_h = roi_h * (1.0f / PH);

    const float* plane = feat + ((size_t)b * C + c) * (size_t)(H * W);

    float acc = 0.0f;
    #pragma unroll
    for (int sy = 0; sy < 2; ++sy) {
        float y = y1 + (float)ph * bin_h + ((float)sy + 0.5f) * bin_h * 0.5f;
        bool vy = (y >= -1.0f) && (y <= (float)H);
        float yc = fmaxf(y, 0.0f);
        int ylo = (int)yc;
        int yhi;
        if (ylo >= H - 1) { ylo = H - 1; yhi = H - 1; yc = (float)(H - 1); }
        else              { yhi = ylo + 1; }
        float ly = yc - (float)ylo, hy = 1.0f - ly;

        #pragma unroll
        for (int sx = 0; sx < 2; ++sx) {
            float x = x1 + (float)pw * bin_w + ((float)sx + 0.5f) * bin_w * 0.5f;
            bool vx = (x >= -1.0f) && (x <= (float)W);
            float xc = fmaxf(x, 0.0f);
            int xlo = (int)xc;
            int xhi;
            if (xlo >= W - 1) { xlo = W - 1; xhi = W - 1; xc = (float)(W - 1); }
            else              { xhi = xlo + 1; }
            float lx = xc - (float)xlo, hx = 1.0f - lx;

            if (vy && vx) {
                float v00 = plane[ylo * W + xlo];
                float v01 = plane[ylo * W + xhi];
                float v10 = plane[yhi * W + xlo];
                float v11 = plane[yhi * W + xhi];
                acc += hy * (hx * v00 + lx * v01) + ly * (hx * v10 + lx * v11);
            }
        }
    }
    out[idx] = acc * 0.25f;
}

extern "C" void kernel_launch(void* const* d_in, const int* in_sizes, int n_in,
                              void* d_out, int out_size, void* d_ws, size_t ws_size,
                              hipStream_t stream) {
    const float* feat = (const float*)d_in[0];
    const float* rois = (const float*)d_in[1];
    float* out = (float*)d_out;

    int total = out_size;  // K * C * PH * PW
    int threads = 256;
    int blocks = (total + threads - 1) / threads;
    roi_align_kernel<<<blocks, threads, 0, stream>>>(feat, rois, out, total);
}

// Round 2
// 192.614 us; speedup vs baseline: 1.7674x; 1.7674x over previous
//
#include <hip/hip_runtime.h>

// RoIAlign (torchvision semantics, aligned=false, sampling_ratio=2)
// features: [N=2, C=256, H=200, W=200] f32
// rois:     [K, 5] f32  (b, x1, y1, x2, y2) raw image coords
// out:      [K, C, 7, 7] f32
constexpr int C = 256, H = 200, W = 200;
constexpr int PH = 7, PW = 7;
constexpr int NSAMP = 14;          // PH * 2 samples per axis
constexpr int CG = 8;              // channels per group (per-XCD L2 slice: 2*8*160KB = 2.56MB)
constexpr int NGROUP = C / CG;     // 32 groups -> 4 phases x 8 XCDs
constexpr float SCALE = 0.125f;

__global__ __launch_bounds__(256) void roi_align_kernel(
    const float* __restrict__ feat, const float* __restrict__ rois,
    float* __restrict__ out, int K)
{
    __shared__ int   s_ylo[NSAMP], s_yhi[NSAMP], s_xlo[NSAMP], s_xhi[NSAMP];
    __shared__ float s_hy[NSAMP],  s_ly[NSAMP],  s_hx[NSAMP],  s_lx[NSAMP];

    int B   = blockIdx.x;
    int xcd = B & 7;               // consecutive blocks round-robin XCDs
    int j   = B >> 3;              // per-XCD sequence: phase-major, roi-minor
    int p   = j / K;
    int k   = j - p * K;
    int cb  = (p * 8 + xcd) * CG;  // channel base for this block

    const float* r = rois + (size_t)k * 5;
    int   b  = (int)r[0];
    float x1 = r[1] * SCALE, y1 = r[2] * SCALE;
    float x2 = r[3] * SCALE, y2 = r[4] * SCALE;
    float bin_w = fmaxf(x2 - x1, 1.0f) * (1.0f / PW);
    float bin_h = fmaxf(y2 - y1, 1.0f) * (1.0f / PH);

    int t = threadIdx.x;
    // per-roi bilinear tables, shared across all channels (validity folded into weights)
    if (t < NSAMP) {
        int ph = t >> 1, s = t & 1;
        float y = y1 + (float)ph * bin_h + ((float)s + 0.5f) * bin_h * 0.5f;
        bool v = (y >= -1.0f) && (y <= (float)H);
        float yc = fmaxf(y, 0.0f);
        int lo = (int)yc, hi;
        if (lo >= H - 1) { lo = H - 1; hi = H - 1; yc = (float)(H - 1); }
        else             { hi = lo + 1; }
        float l = yc - (float)lo;
        s_ylo[t] = lo; s_yhi[t] = hi;
        s_ly[t] = v ? l : 0.0f; s_hy[t] = v ? 1.0f - l : 0.0f;
    } else if (t >= 64 && t < 64 + NSAMP) {
        int i = t - 64;
        int pw = i >> 1, s = i & 1;
        float x = x1 + (float)pw * bin_w + ((float)s + 0.5f) * bin_w * 0.5f;
        bool v = (x >= -1.0f) && (x <= (float)W);
        float xc = fmaxf(x, 0.0f);
        int lo = (int)xc, hi;
        if (lo >= W - 1) { lo = W - 1; hi = W - 1; xc = (float)(W - 1); }
        else             { hi = lo + 1; }
        float l = xc - (float)lo;
        s_xlo[i] = lo; s_xhi[i] = hi;
        s_lx[i] = v ? l : 0.0f; s_hx[i] = v ? 1.0f - l : 0.0f;
    }
    __syncthreads();

    const float* img = feat + (size_t)b * (C * H * W);
    float* out_base = out + (size_t)k * (C * PH * PW) + (size_t)cb * (PH * PW);

    for (int i = t; i < CG * PH * PW; i += 256) {
        int cl  = i / (PH * PW);
        int bin = i - cl * (PH * PW);
        int ph  = bin / PW;
        int pw  = bin - ph * PW;
        const float* plane = img + (size_t)(cb + cl) * (H * W);

        float acc = 0.0f;
        #pragma unroll
        for (int sy = 0; sy < 2; ++sy) {
            int ysi = ph * 2 + sy;
            int ylo = s_ylo[ysi], yhi = s_yhi[ysi];
            float ly = s_ly[ysi], hy = s_hy[ysi];
            const float* rowlo = plane + ylo * W;
            const float* rowhi = plane + yhi * W;
            #pragma unroll
            for (int sx = 0; sx < 2; ++sx) {
                int xsi = pw * 2 + sx;
                int xlo = s_xlo[xsi], xhi = s_xhi[xsi];
                float lx = s_lx[xsi], hx = s_hx[xsi];
                acc += hy * (hx * rowlo[xlo] + lx * rowlo[xhi])
                     + ly * (hx * rowhi[xlo] + lx * rowhi[xhi]);
            }
        }
        // streaming store: don't let the 50MB output evict the resident channel slice
        __builtin_nontemporal_store(acc * 0.25f, &out_base[i]);
    }
}

extern "C" void kernel_launch(void* const* d_in, const int* in_sizes, int n_in,
                              void* d_out, int out_size, void* d_ws, size_t ws_size,
                              hipStream_t stream) {
    const float* feat = (const float*)d_in[0];
    const float* rois = (const float*)d_in[1];
    float* out = (float*)d_out;

    int K = in_sizes[1] / 5;
    int blocks = K * NGROUP;   // phase-major per XCD: xcd = B&7, phase = (B>>3)/K
    roi_align_kernel<<<blocks, 256, 0, stream>>>(feat, rois, out, K);
}